// Round 7
// baseline (182.136 us; speedup 1.0000x reference)
//
#include <hip/hip_runtime.h>
#include <cstdint>
#include <cstddef>

typedef __attribute__((ext_vector_type(8))) short short8;
typedef __attribute__((ext_vector_type(4))) float floatx4;
typedef __attribute__((ext_vector_type(4))) short short4v;
typedef unsigned short u16;
typedef unsigned int u32;

#define B_   2
#define T_   2048
#define D_   1024
#define H_   16
#define HKV_ 4
#define HD_  64
#define KV_  256
#define M_   4096   // B*T
#define QS_  1536   // fused QKV row stride

#define NX   4194304
#define NWQ  1048576
#define NWK  262144
#define NWV  262144
#define NWP  1048576
#define NCAST (NX + NWQ + NWK + NWV + NWP)
#define CAST_BLOCKS (NCAST / 1024)
#define TAB_BLOCKS  256

__device__ __forceinline__ float b2f(u16 u) {
    union { u32 i; float f; } v; v.i = ((u32)u) << 16; return v.f;
}
__device__ __forceinline__ u16 f2b(float f) {
    union { float f; u32 i; } v; v.f = f;
    u32 r = v.i + 0x7FFF + ((v.i >> 16) & 1);
    return (u16)(r >> 16);
}
__device__ __forceinline__ u32 pack_hi(float a, float b) {
    union { float f; u32 u; } ua, ub; ua.f = a; ub.f = b;
    return (ua.u >> 16) | (ub.u & 0xFFFF0000u);
}

__device__ __forceinline__ void async16(const u16* g, u16* l) {
    __builtin_amdgcn_global_load_lds(
        (const __attribute__((address_space(1))) u32*)g,
        (__attribute__((address_space(3))) u32*)l, 16, 0, 0);
}

// ---------------------------------------------------------------------------
// prep: all fp32->bf16 casts + RoPE cos/sin table.
// ---------------------------------------------------------------------------
__global__ __launch_bounds__(256) void prep(const float* __restrict__ x,
                                            const float* __restrict__ wq,
                                            const float* __restrict__ wk,
                                            const float* __restrict__ wv,
                                            const float* __restrict__ wp,
                                            u16* __restrict__ dst,
                                            float2* __restrict__ tab) {
    int blk = blockIdx.x;
    if (blk < CAST_BLOCKS) {
        int i = blk * 1024 + threadIdx.x * 4;
        const float* src; int off;
        if      (i < NX)                  { src = x;  off = i; }
        else if (i < NX+NWQ)              { src = wq; off = i - NX; }
        else if (i < NX+NWQ+NWK)          { src = wk; off = i - (NX+NWQ); }
        else if (i < NX+NWQ+NWK+NWV)      { src = wv; off = i - (NX+NWQ+NWK); }
        else                              { src = wp; off = i - (NX+NWQ+NWK+NWV); }
        float4 v = *(const float4*)(src + off);
        short4v o;
        o.x = (short)f2b(v.x); o.y = (short)f2b(v.y);
        o.z = (short)f2b(v.z); o.w = (short)f2b(v.w);
        *(short4v*)(dst + i) = o;
    } else {
        int idx = (blk - CAST_BLOCKS) * 256 + threadIdx.x;
        int t = idx >> 5, i = idx & 31;
        float freq = exp2f(-(float)i * (13.287712379549449f / 32.0f));
        float ang = (float)t * freq;
        tab[idx] = make_float2(cosf(ang), sinf(ang));
    }
}

// ---------------------------------------------------------------------------
// QKV GEMM, DOUBLE-BUFFERED LDS (1 barrier / K-iter), fused epilogue:
// RMSNorm+RoPE+gain for Q/K columns, transposed scatter to Vt for V columns.
// ---------------------------------------------------------------------------
__global__ __launch_bounds__(256) void gemm_qkv(const u16* __restrict__ A,
                                                const u16* __restrict__ W,
                                                u16* __restrict__ C,
                                                u16* __restrict__ Vt,
                                                const float* __restrict__ gain,
                                                const float2* __restrict__ tab) {
    const int K = D_;
    __shared__ u16 As[2][128 * 32];
    __shared__ u16 Bs[2][128 * 32];
    const int t = threadIdx.x;
    const int wave = t >> 6, lane = t & 63;
    const int quad = lane >> 4, l16 = lane & 15;
    const int wm = (wave >> 1) * 64, wn = (wave & 1) * 64;
    const int m0 = blockIdx.y * 128, n0 = blockIdx.x * 128;

    floatx4 acc[4][4];
#pragma unroll
    for (int i = 0; i < 4; i++)
#pragma unroll
        for (int j = 0; j < 4; j++) acc[i][j] = (floatx4){0.f, 0.f, 0.f, 0.f};

    const int sr = t >> 2, sc = (t & 3) * 8;
    const u16* ga = A + (size_t)(m0 + sr) * K + sc;
    const u16* gb = W + (size_t)(n0 + sr) * K + sc;

    // stage tile 0 into buf 0
    async16(ga, As[0] + t * 8);
    async16(ga + (size_t)64 * K, As[0] + t * 8 + 64 * 32);
    async16(gb, Bs[0] + t * 8);
    async16(gb + (size_t)64 * K, Bs[0] + t * 8 + 64 * 32);

    int cur = 0;
    for (int kt = 0; kt < K; kt += 32) {
        __syncthreads();          // buf[cur] staged; all reads of buf[cur^1] done
        if (kt + 32 < K) {
            const u16* ga2 = ga + kt + 32;
            const u16* gb2 = gb + kt + 32;
            u16* lA = As[cur ^ 1] + t * 8;
            u16* lB = Bs[cur ^ 1] + t * 8;
            async16(ga2, lA);
            async16(ga2 + (size_t)64 * K, lA + 64 * 32);
            async16(gb2, lB);
            async16(gb2 + (size_t)64 * K, lB + 64 * 32);
        }
        short8 af[4], bf[4];
#pragma unroll
        for (int mt = 0; mt < 4; mt++)
            af[mt] = *(const short8*)(As[cur] + (wm + mt * 16 + l16) * 32 + quad * 8);
#pragma unroll
        for (int nt = 0; nt < 4; nt++)
            bf[nt] = *(const short8*)(Bs[cur] + (wn + nt * 16 + l16) * 32 + quad * 8);
#pragma unroll
        for (int mt = 0; mt < 4; mt++)
#pragma unroll
            for (int nt = 0; nt < 4; nt++)
                acc[mt][nt] = __builtin_amdgcn_mfma_f32_16x16x32_bf16(
                    af[mt], bf[nt], acc[mt][nt], 0, 0, 0);
        cur ^= 1;
    }

    const int col0 = n0 + wn;
    if (col0 < 1280) {
        float gs = (col0 < 1024)
                 ? gain[col0 >> 6] * (0.125f * 1.4426950408889634f)
                 : 1.0f;
#pragma unroll
        for (int mt = 0; mt < 4; mt++)
#pragma unroll
            for (int r = 0; r < 4; r++) {
                int row = m0 + wm + mt * 16 + quad * 4 + r;
                int tt = row & (T_ - 1);
                float v0 = acc[mt][0][r], v1 = acc[mt][1][r];
                float v2 = acc[mt][2][r], v3 = acc[mt][3][r];
                float ss = v0 * v0 + v1 * v1 + v2 * v2 + v3 * v3;
                ss += __shfl_xor(ss, 1); ss += __shfl_xor(ss, 2);
                ss += __shfl_xor(ss, 4); ss += __shfl_xor(ss, 8);
                float inv = rsqrtf(ss * (1.0f / 64.0f) + 1.1920929e-7f);
                v0 *= inv; v1 *= inv; v2 *= inv; v3 *= inv;
                float2 cs0 = tab[tt * 32 + l16];
                float2 cs1 = tab[tt * 32 + 16 + l16];
                float o0 = (v0 * cs0.x + v2 * cs0.y) * gs;
                float o1 = (v1 * cs1.x + v3 * cs1.y) * gs;
                float o2 = (v2 * cs0.x - v0 * cs0.y) * gs;
                float o3 = (v3 * cs1.x - v1 * cs1.y) * gs;
                u16* cp = C + (size_t)row * QS_ + col0 + l16;
                cp[0]  = f2b(o0);
                cp[16] = f2b(o1);
                cp[32] = f2b(o2);
                cp[48] = f2b(o3);
            }
    } else {
        const int g = (col0 - 1280) >> 6;
#pragma unroll
        for (int mt = 0; mt < 4; mt++)
#pragma unroll
            for (int r = 0; r < 4; r++) {
                int row = m0 + wm + mt * 16 + quad * 4 + r;
                int tt = row & (T_ - 1);
                int bb = row >> 11;
#pragma unroll
                for (int nt = 0; nt < 4; nt++)
                    Vt[(size_t)((bb * 4 + g) * 64 + nt * 16 + l16) * T_ + tt] =
                        f2b(acc[mt][nt][r]);
            }
    }
}

// ---------------------------------------------------------------------------
// generic GEMM (output projection, fp32 out), DOUBLE-BUFFERED LDS.
// ---------------------------------------------------------------------------
template <typename OutT>
__global__ __launch_bounds__(256) void gemm128(const u16* __restrict__ A,
                                               const u16* __restrict__ W,
                                               OutT* __restrict__ C,
                                               int M, int N, int K, int ldc) {
    __shared__ u16 As[2][128 * 32];
    __shared__ u16 Bs[2][128 * 32];
    const int t = threadIdx.x;
    const int wave = t >> 6, lane = t & 63;
    const int quad = lane >> 4, l16 = lane & 15;
    const int wm = (wave >> 1) * 64, wn = (wave & 1) * 64;
    const int m0 = blockIdx.y * 128, n0 = blockIdx.x * 128;

    floatx4 acc[4][4];
#pragma unroll
    for (int i = 0; i < 4; i++)
#pragma unroll
        for (int j = 0; j < 4; j++) acc[i][j] = (floatx4){0.f, 0.f, 0.f, 0.f};

    const int sr = t >> 2, sc = (t & 3) * 8;
    const u16* ga = A + (size_t)(m0 + sr) * K + sc;
    const u16* gb = W + (size_t)(n0 + sr) * K + sc;

    async16(ga, As[0] + t * 8);
    async16(ga + (size_t)64 * K, As[0] + t * 8 + 64 * 32);
    async16(gb, Bs[0] + t * 8);
    async16(gb + (size_t)64 * K, Bs[0] + t * 8 + 64 * 32);

    int cur = 0;
    for (int kt = 0; kt < K; kt += 32) {
        __syncthreads();
        if (kt + 32 < K) {
            const u16* ga2 = ga + kt + 32;
            const u16* gb2 = gb + kt + 32;
            u16* lA = As[cur ^ 1] + t * 8;
            u16* lB = Bs[cur ^ 1] + t * 8;
            async16(ga2, lA);
            async16(ga2 + (size_t)64 * K, lA + 64 * 32);
            async16(gb2, lB);
            async16(gb2 + (size_t)64 * K, lB + 64 * 32);
        }
        short8 af[4], bf[4];
#pragma unroll
        for (int mt = 0; mt < 4; mt++)
            af[mt] = *(const short8*)(As[cur] + (wm + mt * 16 + l16) * 32 + quad * 8);
#pragma unroll
        for (int nt = 0; nt < 4; nt++)
            bf[nt] = *(const short8*)(Bs[cur] + (wn + nt * 16 + l16) * 32 + quad * 8);
#pragma unroll
        for (int mt = 0; mt < 4; mt++)
#pragma unroll
            for (int nt = 0; nt < 4; nt++)
                acc[mt][nt] = __builtin_amdgcn_mfma_f32_16x16x32_bf16(
                    af[mt], bf[nt], acc[mt][nt], 0, 0, 0);
        cur ^= 1;
    }

#pragma unroll
    for (int mt = 0; mt < 4; mt++)
#pragma unroll
        for (int nt = 0; nt < 4; nt++)
#pragma unroll
            for (int r = 0; r < 4; r++) {
                int row = m0 + wm + mt * 16 + quad * 4 + r;
                int col = n0 + wn + nt * 16 + l16;
                float val = acc[mt][nt][r];
                if constexpr (sizeof(OutT) == 4) C[(size_t)row * ldc + col] = val;
                else                             C[(size_t)row * ldc + col] = (OutT)f2b(val);
            }
}

// ---------------------------------------------------------------------------
// Flash attention (causal), no-max softmax, DOUBLE-BUFFERED K/V LDS
// (1 barrier / tile-iter; DMA issued right after the barrier).
// Complementary q-tile pair (xp, 31-xp); S^T trick; l via all-ones MFMA.
// ---------------------------------------------------------------------------
__global__ __launch_bounds__(256) void flash(const u16* __restrict__ QKV,
                                             const u16* __restrict__ Vtr,
                                             u16* __restrict__ Y) {
    const int xp = blockIdx.x;
    const int h  = blockIdx.y;
    const int b  = blockIdx.z;
    const int g  = h >> 2;
    const int w    = threadIdx.x >> 6;
    const int lane = threadIdx.x & 63;
    const int quad = lane >> 4, l16 = lane & 15;

    __shared__ u16 Kt[2][64 * 64];
    __shared__ u16 Vs[2][64 * 64];
    __shared__ __align__(16) u16 P[4][2][16][72];

    const int mA = xp * 64 + w * 16;
    const int mB = (31 - xp) * 64 + w * 16;
    const int nA = xp + 1;
    const int nB = 32 - xp;

    const u16* qpA = QKV + (size_t)(b * T_ + mA + l16) * QS_ + h * HD_ + quad * 8;
    const u16* qpB = QKV + (size_t)(b * T_ + mB + l16) * QS_ + h * HD_ + quad * 8;
    short8 aqA0 = *(const short8*)(qpA);
    short8 aqA1 = *(const short8*)(qpA + 32);
    short8 aqB0 = *(const short8*)(qpB);
    short8 aqB1 = *(const short8*)(qpB + 32);

    short8 ones;
#pragma unroll
    for (int i = 0; i < 8; i++) ones[i] = (short)0x3F80;

    floatx4 accA[4], accB[4];
#pragma unroll
    for (int i = 0; i < 4; i++) {
        accA[i] = (floatx4){0.f, 0.f, 0.f, 0.f};
        accB[i] = (floatx4){0.f, 0.f, 0.f, 0.f};
    }
    floatx4 lAcc = (floatx4){0.f, 0.f, 0.f, 0.f};
    floatx4 lBcc = (floatx4){0.f, 0.f, 0.f, 0.f};

    const int srow = w * 16 + (lane >> 3);
    const int sseg = (lane & 7) ^ ((lane >> 3) & 7);
    const u16* kg = QKV + (size_t)(b * T_ + srow) * QS_ + D_ + g * 64 + sseg * 8;
    const u16* vg = Vtr + (size_t)((b * 4 + g) * 64 + srow) * T_ + sseg * 8;

    const int sw0 = (quad ^ (l16 & 7)) * 8;
    const int sw1 = ((4 + quad) ^ (l16 & 7)) * 8;

    // stage tile 0 into buf 0
    async16(kg, Kt[0] + w * 1024 + lane * 8);
    async16(kg + (size_t)8 * QS_, Kt[0] + w * 1024 + lane * 8 + 512);
    async16(vg, Vs[0] + w * 1024 + lane * 8);
    async16(vg + (size_t)8 * T_, Vs[0] + w * 1024 + lane * 8 + 512);

    int cur = 0;
    for (int tk = 0; tk < nB; tk++) {
        const bool dual = (tk < nA);
        __syncthreads();            // buf[cur] staged; reads of buf[cur^1] done
        if (tk + 1 < nB) {
            kg += (size_t)64 * QS_;
            vg += 64;
            u16* klds = Kt[cur ^ 1] + w * 1024 + lane * 8;
            u16* vlds = Vs[cur ^ 1] + w * 1024 + lane * 8;
            async16(kg, klds);
            async16(kg + (size_t)8 * QS_, klds + 512);
            async16(vg, vlds);
            async16(vg + (size_t)8 * T_, vlds + 512);
        }

        floatx4 SB[4], SA[4];
#pragma unroll
        for (int nt = 0; nt < 4; nt++) {
            const u16* kr = Kt[cur] + (nt * 16 + l16) * 64;
            short8 kf0 = *(const short8*)(kr + sw0);
            short8 kf1 = *(const short8*)(kr + sw1);
            SB[nt] = (floatx4){0.f, 0.f, 0.f, 0.f};
            SB[nt] = __builtin_amdgcn_mfma_f32_16x16x32_bf16(kf0, aqB0, SB[nt], 0, 0, 0);
            SB[nt] = __builtin_amdgcn_mfma_f32_16x16x32_bf16(kf1, aqB1, SB[nt], 0, 0, 0);
            if (dual) {
                SA[nt] = (floatx4){0.f, 0.f, 0.f, 0.f};
                SA[nt] = __builtin_amdgcn_mfma_f32_16x16x32_bf16(kf0, aqA0, SA[nt], 0, 0, 0);
                SA[nt] = __builtin_amdgcn_mfma_f32_16x16x32_bf16(kf1, aqA1, SA[nt], 0, 0, 0);
            }
        }
        short8 vf[4][2];
#pragma unroll
        for (int dd = 0; dd < 4; dd++) {
            const u16* vr = Vs[cur] + (dd * 16 + l16) * 64;
            vf[dd][0] = *(const short8*)(vr + sw0);
            vf[dd][1] = *(const short8*)(vr + sw1);
        }

        const bool maskB = (tk == nB - 1);
        const int qB = mB + l16;
#pragma unroll
        for (int nt = 0; nt < 4; nt++) {
            float p[4];
#pragma unroll
            for (int r = 0; r < 4; r++) {
                float e = __builtin_amdgcn_exp2f(SB[nt][r]);
                if (maskB) {
                    int key = tk * 64 + nt * 16 + quad * 4 + r;
                    e = (key <= qB) ? e : 0.f;
                }
                p[r] = e;
            }
            uint2 pw; pw.x = pack_hi(p[0], p[1]); pw.y = pack_hi(p[2], p[3]);
            *(uint2*)&P[w][1][l16][nt * 16 + quad * 4] = pw;
        }
        short8 pfB0 = *(const short8*)&P[w][1][l16][quad * 8];
        short8 pfB1 = *(const short8*)&P[w][1][l16][quad * 8 + 32];
#pragma unroll
        for (int dd = 0; dd < 4; dd++) {
            accB[dd] = __builtin_amdgcn_mfma_f32_16x16x32_bf16(pfB0, vf[dd][0], accB[dd], 0, 0, 0);
            accB[dd] = __builtin_amdgcn_mfma_f32_16x16x32_bf16(pfB1, vf[dd][1], accB[dd], 0, 0, 0);
        }
        lBcc = __builtin_amdgcn_mfma_f32_16x16x32_bf16(pfB0, ones, lBcc, 0, 0, 0);
        lBcc = __builtin_amdgcn_mfma_f32_16x16x32_bf16(pfB1, ones, lBcc, 0, 0, 0);

        if (dual) {
            const bool maskA = (tk == nA - 1);
            const int qA = mA + l16;
#pragma unroll
            for (int nt = 0; nt < 4; nt++) {
                float p[4];
#pragma unroll
                for (int r = 0; r < 4; r++) {
                    float e = __builtin_amdgcn_exp2f(SA[nt][r]);
                    if (maskA) {
                        int key = tk * 64 + nt * 16 + quad * 4 + r;
                        e = (key <= qA) ? e : 0.f;
                    }
                    p[r] = e;
                }
                uint2 pw; pw.x = pack_hi(p[0], p[1]); pw.y = pack_hi(p[2], p[3]);
                *(uint2*)&P[w][0][l16][nt * 16 + quad * 4] = pw;
            }
            short8 pfA0 = *(const short8*)&P[w][0][l16][quad * 8];
            short8 pfA1 = *(const short8*)&P[w][0][l16][quad * 8 + 32];
#pragma unroll
            for (int dd = 0; dd < 4; dd++) {
                accA[dd] = __builtin_amdgcn_mfma_f32_16x16x32_bf16(pfA0, vf[dd][0], accA[dd], 0, 0, 0);
                accA[dd] = __builtin_amdgcn_mfma_f32_16x16x32_bf16(pfA1, vf[dd][1], accA[dd], 0, 0, 0);
            }
            lAcc = __builtin_amdgcn_mfma_f32_16x16x32_bf16(pfA0, ones, lAcc, 0, 0, 0);
            lAcc = __builtin_amdgcn_mfma_f32_16x16x32_bf16(pfA1, ones, lAcc, 0, 0, 0);
        }
        cur ^= 1;
    }

#pragma unroll
    for (int r = 0; r < 4; r++) {
        float invA = 1.0f / lAcc[r];
        float invB = 1.0f / lBcc[r];
        int rowA = mA + quad * 4 + r;
        int rowB = mB + quad * 4 + r;
        u16* ypA = Y + (size_t)(b * T_ + rowA) * D_ + h * HD_ + l16;
        u16* ypB = Y + (size_t)(b * T_ + rowB) * D_ + h * HD_ + l16;
#pragma unroll
        for (int dd = 0; dd < 4; dd++) {
            ypA[dd * 16] = f2b(accA[dd][r] * invA);
            ypB[dd * 16] = f2b(accB[dd][r] * invB);
        }
    }
}

// ---------------------------------------------------------------------------
extern "C" void kernel_launch(void* const* d_in, const int* in_sizes, int n_in,
                              void* d_out, int out_size, void* d_ws, size_t ws_size,
                              hipStream_t stream) {
    const float* x    = (const float*)d_in[0];
    const float* Wq   = (const float*)d_in[1];
    const float* Wk   = (const float*)d_in[2];
    const float* Wv   = (const float*)d_in[3];
    const float* Wp   = (const float*)d_in[4];
    const float* gain = (const float*)d_in[5];
    float* out = (float*)d_out;

    u16* xb   = (u16*)d_ws;
    u16* Wcat = xb + (size_t)NX;
    u16* Wpb  = Wcat + (size_t)(NWQ + NWK + NWV);
    u16* QKV  = Wpb + (size_t)NWP;
    u16* Vt   = QKV + (size_t)M_ * QS_;
    u16* Y    = Vt + (size_t)M_ * KV_;
    float2* tab = (float2*)(Y + (size_t)M_ * D_);

    prep<<<CAST_BLOCKS + TAB_BLOCKS, 256, 0, stream>>>(x, Wq, Wk, Wv, Wp, xb, tab);

    gemm_qkv<<<dim3(QS_ / 128, M_ / 128), 256, 0, stream>>>(xb, Wcat, QKV, Vt,
                                                            gain, tab);

    flash<<<dim3(16, H_, B_), 256, 0, stream>>>(QKV, Vt, Y);

    gemm128<float><<<dim3(D_ / 128, M_ / 128), 256, 0, stream>>>(Y, Wpb, out,
                                                                 M_, D_, D_, D_);
}

// Round 8
// 174.070 us; speedup vs baseline: 1.0463x; 1.0463x over previous
//
#include <hip/hip_runtime.h>
#include <cstdint>
#include <cstddef>

typedef __attribute__((ext_vector_type(8))) short short8;
typedef __attribute__((ext_vector_type(4))) float floatx4;
typedef __attribute__((ext_vector_type(4))) short short4v;
typedef unsigned short u16;
typedef unsigned int u32;

#define B_   2
#define T_   2048
#define D_   1024
#define H_   16
#define HKV_ 4
#define HD_  64
#define KV_  256
#define M_   4096   // B*T
#define QS_  1536   // fused QKV row stride

#define NX   4194304
#define NWQ  1048576
#define NWK  262144
#define NWV  262144
#define NWP  1048576
#define NCAST (NX + NWQ + NWK + NWV + NWP)
#define CAST_BLOCKS (NCAST / 1024)
#define TAB_BLOCKS  256

__device__ __forceinline__ float b2f(u16 u) {
    union { u32 i; float f; } v; v.i = ((u32)u) << 16; return v.f;
}
__device__ __forceinline__ u16 f2b(float f) {
    union { float f; u32 i; } v; v.f = f;
    u32 r = v.i + 0x7FFF + ((v.i >> 16) & 1);
    return (u16)(r >> 16);
}
__device__ __forceinline__ u32 pack_hi(float a, float b) {
    union { float f; u32 u; } ua, ub; ua.f = a; ub.f = b;
    return (ua.u >> 16) | (ub.u & 0xFFFF0000u);
}

__device__ __forceinline__ void async16(const u16* g, u16* l) {
    __builtin_amdgcn_global_load_lds(
        (const __attribute__((address_space(1))) u32*)g,
        (__attribute__((address_space(3))) u32*)l, 16, 0, 0);
}

// ---------------------------------------------------------------------------
// prep: all fp32->bf16 casts + RoPE cos/sin table.
// ---------------------------------------------------------------------------
__global__ __launch_bounds__(256) void prep(const float* __restrict__ x,
                                            const float* __restrict__ wq,
                                            const float* __restrict__ wk,
                                            const float* __restrict__ wv,
                                            const float* __restrict__ wp,
                                            u16* __restrict__ dst,
                                            float2* __restrict__ tab) {
    int blk = blockIdx.x;
    if (blk < CAST_BLOCKS) {
        int i = blk * 1024 + threadIdx.x * 4;
        const float* src; int off;
        if      (i < NX)                  { src = x;  off = i; }
        else if (i < NX+NWQ)              { src = wq; off = i - NX; }
        else if (i < NX+NWQ+NWK)          { src = wk; off = i - (NX+NWQ); }
        else if (i < NX+NWQ+NWK+NWV)      { src = wv; off = i - (NX+NWQ+NWK); }
        else                              { src = wp; off = i - (NX+NWQ+NWK+NWV); }
        float4 v = *(const float4*)(src + off);
        short4v o;
        o.x = (short)f2b(v.x); o.y = (short)f2b(v.y);
        o.z = (short)f2b(v.z); o.w = (short)f2b(v.w);
        *(short4v*)(dst + i) = o;
    } else {
        int idx = (blk - CAST_BLOCKS) * 256 + threadIdx.x;
        int t = idx >> 5, i = idx & 31;
        float freq = exp2f(-(float)i * (13.287712379549449f / 32.0f));
        float ang = (float)t * freq;
        tab[idx] = make_float2(cosf(ang), sinf(ang));
    }
}

// ---------------------------------------------------------------------------
// QKV GEMM: 128x64 tile (4 waves x [32 rows x 64 cols]), BK=32, dbuf LDS.
// Grid (1536/64, 4096/128) = 768 blocks = 3/CU. Fused epilogue:
// RMSNorm+RoPE+gain for Q/K cols, transposed scatter to Vt for V cols.
// ---------------------------------------------------------------------------
__global__ __launch_bounds__(256, 3) void gemm_qkv(const u16* __restrict__ A,
                                                   const u16* __restrict__ W,
                                                   u16* __restrict__ C,
                                                   u16* __restrict__ Vt,
                                                   const float* __restrict__ gain,
                                                   const float2* __restrict__ tab) {
    const int K = D_;
    __shared__ u16 As[2][128 * 32];
    __shared__ u16 Bs[2][64 * 32];
    const int t = threadIdx.x;
    const int wave = t >> 6, lane = t & 63;
    const int quad = lane >> 4, l16 = lane & 15;
    const int wm = wave * 32;
    const int m0 = blockIdx.y * 128, n0 = blockIdx.x * 64;

    floatx4 acc[2][4];
#pragma unroll
    for (int i = 0; i < 2; i++)
#pragma unroll
        for (int j = 0; j < 4; j++) acc[i][j] = (floatx4){0.f, 0.f, 0.f, 0.f};

    const int sr = t >> 2, sc = (t & 3) * 8;
    const u16* ga = A + (size_t)(m0 + sr) * K + sc;
    const u16* gb = W + (size_t)(n0 + sr) * K + sc;

    async16(ga, As[0] + t * 8);
    async16(ga + (size_t)64 * K, As[0] + t * 8 + 64 * 32);
    async16(gb, Bs[0] + t * 8);

    int cur = 0;
    for (int kt = 0; kt < K; kt += 32) {
        __syncthreads();
        if (kt + 32 < K) {
            const u16* ga2 = ga + kt + 32;
            const u16* gb2 = gb + kt + 32;
            async16(ga2, As[cur ^ 1] + t * 8);
            async16(ga2 + (size_t)64 * K, As[cur ^ 1] + t * 8 + 64 * 32);
            async16(gb2, Bs[cur ^ 1] + t * 8);
        }
        short8 af[2], bf[4];
#pragma unroll
        for (int mt = 0; mt < 2; mt++)
            af[mt] = *(const short8*)(As[cur] + (wm + mt * 16 + l16) * 32 + quad * 8);
#pragma unroll
        for (int nt = 0; nt < 4; nt++)
            bf[nt] = *(const short8*)(Bs[cur] + (nt * 16 + l16) * 32 + quad * 8);
#pragma unroll
        for (int mt = 0; mt < 2; mt++)
#pragma unroll
            for (int nt = 0; nt < 4; nt++)
                acc[mt][nt] = __builtin_amdgcn_mfma_f32_16x16x32_bf16(
                    af[mt], bf[nt], acc[mt][nt], 0, 0, 0);
        cur ^= 1;
    }

    const int col0 = n0;               // 64-aligned: exactly one head-block
    if (col0 < 1280) {
        float gs = (col0 < 1024)
                 ? gain[col0 >> 6] * (0.125f * 1.4426950408889634f)
                 : 1.0f;
#pragma unroll
        for (int mt = 0; mt < 2; mt++)
#pragma unroll
            for (int r = 0; r < 4; r++) {
                int row = m0 + wm + mt * 16 + quad * 4 + r;
                int tt = row & (T_ - 1);
                float v0 = acc[mt][0][r], v1 = acc[mt][1][r];
                float v2 = acc[mt][2][r], v3 = acc[mt][3][r];
                float ss = v0 * v0 + v1 * v1 + v2 * v2 + v3 * v3;
                ss += __shfl_xor(ss, 1); ss += __shfl_xor(ss, 2);
                ss += __shfl_xor(ss, 4); ss += __shfl_xor(ss, 8);
                float inv = rsqrtf(ss * (1.0f / 64.0f) + 1.1920929e-7f);
                v0 *= inv; v1 *= inv; v2 *= inv; v3 *= inv;
                float2 cs0 = tab[tt * 32 + l16];
                float2 cs1 = tab[tt * 32 + 16 + l16];
                float o0 = (v0 * cs0.x + v2 * cs0.y) * gs;
                float o1 = (v1 * cs1.x + v3 * cs1.y) * gs;
                float o2 = (v2 * cs0.x - v0 * cs0.y) * gs;
                float o3 = (v3 * cs1.x - v1 * cs1.y) * gs;
                u16* cp = C + (size_t)row * QS_ + col0 + l16;
                cp[0]  = f2b(o0);
                cp[16] = f2b(o1);
                cp[32] = f2b(o2);
                cp[48] = f2b(o3);
            }
    } else {
        const int g = (col0 - 1280) >> 6;
#pragma unroll
        for (int mt = 0; mt < 2; mt++)
#pragma unroll
            for (int r = 0; r < 4; r++) {
                int row = m0 + wm + mt * 16 + quad * 4 + r;
                int tt = row & (T_ - 1);
                int bb = row >> 11;
#pragma unroll
                for (int nt = 0; nt < 4; nt++)
                    Vt[(size_t)((bb * 4 + g) * 64 + nt * 16 + l16) * T_ + tt] =
                        f2b(acc[mt][nt][r]);
            }
    }
}

// ---------------------------------------------------------------------------
// Output-projection GEMM: 128x64 tile, same structure, fp32 out.
// Grid (1024/64, 4096/128) = 512 blocks = 2/CU.
// ---------------------------------------------------------------------------
__global__ __launch_bounds__(256, 3) void gemm_proj(const u16* __restrict__ A,
                                                    const u16* __restrict__ W,
                                                    float* __restrict__ C) {
    const int K = D_;
    __shared__ u16 As[2][128 * 32];
    __shared__ u16 Bs[2][64 * 32];
    const int t = threadIdx.x;
    const int wave = t >> 6, lane = t & 63;
    const int quad = lane >> 4, l16 = lane & 15;
    const int wm = wave * 32;
    const int m0 = blockIdx.y * 128, n0 = blockIdx.x * 64;

    floatx4 acc[2][4];
#pragma unroll
    for (int i = 0; i < 2; i++)
#pragma unroll
        for (int j = 0; j < 4; j++) acc[i][j] = (floatx4){0.f, 0.f, 0.f, 0.f};

    const int sr = t >> 2, sc = (t & 3) * 8;
    const u16* ga = A + (size_t)(m0 + sr) * K + sc;
    const u16* gb = W + (size_t)(n0 + sr) * K + sc;

    async16(ga, As[0] + t * 8);
    async16(ga + (size_t)64 * K, As[0] + t * 8 + 64 * 32);
    async16(gb, Bs[0] + t * 8);

    int cur = 0;
    for (int kt = 0; kt < K; kt += 32) {
        __syncthreads();
        if (kt + 32 < K) {
            const u16* ga2 = ga + kt + 32;
            const u16* gb2 = gb + kt + 32;
            async16(ga2, As[cur ^ 1] + t * 8);
            async16(ga2 + (size_t)64 * K, As[cur ^ 1] + t * 8 + 64 * 32);
            async16(gb2, Bs[cur ^ 1] + t * 8);
        }
        short8 af[2], bf[4];
#pragma unroll
        for (int mt = 0; mt < 2; mt++)
            af[mt] = *(const short8*)(As[cur] + (wm + mt * 16 + l16) * 32 + quad * 8);
#pragma unroll
        for (int nt = 0; nt < 4; nt++)
            bf[nt] = *(const short8*)(Bs[cur] + (nt * 16 + l16) * 32 + quad * 8);
#pragma unroll
        for (int mt = 0; mt < 2; mt++)
#pragma unroll
            for (int nt = 0; nt < 4; nt++)
                acc[mt][nt] = __builtin_amdgcn_mfma_f32_16x16x32_bf16(
                    af[mt], bf[nt], acc[mt][nt], 0, 0, 0);
        cur ^= 1;
    }

#pragma unroll
    for (int mt = 0; mt < 2; mt++)
#pragma unroll
        for (int nt = 0; nt < 4; nt++)
#pragma unroll
            for (int r = 0; r < 4; r++) {
                int row = m0 + wm + mt * 16 + quad * 4 + r;
                int col = n0 + nt * 16 + l16;
                C[(size_t)row * D_ + col] = acc[mt][nt][r];
            }
}

// ---------------------------------------------------------------------------
// Flash attention (causal), no-max softmax (|s|<=8 post-RMSNorm), exp2 via
// v_exp_f32 (log2e folded into Q). Complementary q-tile pair (xp, 31-xp):
// uniform 33 tile-units/wave. K/V staged single-buffered via global_load_lds
// (XOR-swizzled); S^T trick for packed P writes; l via all-ones MFMA.
// ---------------------------------------------------------------------------
__global__ __launch_bounds__(256) void flash(const u16* __restrict__ QKV,
                                             const u16* __restrict__ Vtr,
                                             u16* __restrict__ Y) {
    const int xp = blockIdx.x;
    const int h  = blockIdx.y;
    const int b  = blockIdx.z;
    const int g  = h >> 2;
    const int w    = threadIdx.x >> 6;
    const int lane = threadIdx.x & 63;
    const int quad = lane >> 4, l16 = lane & 15;

    __shared__ u16 Kt[64 * 64];
    __shared__ u16 Vs[64 * 64];
    __shared__ __align__(16) u16 P[4][2][16][72];

    const int mA = xp * 64 + w * 16;
    const int mB = (31 - xp) * 64 + w * 16;
    const int nA = xp + 1;
    const int nB = 32 - xp;

    const u16* qpA = QKV + (size_t)(b * T_ + mA + l16) * QS_ + h * HD_ + quad * 8;
    const u16* qpB = QKV + (size_t)(b * T_ + mB + l16) * QS_ + h * HD_ + quad * 8;
    short8 aqA0 = *(const short8*)(qpA);
    short8 aqA1 = *(const short8*)(qpA + 32);
    short8 aqB0 = *(const short8*)(qpB);
    short8 aqB1 = *(const short8*)(qpB + 32);

    short8 ones;
#pragma unroll
    for (int i = 0; i < 8; i++) ones[i] = (short)0x3F80;

    floatx4 accA[4], accB[4];
#pragma unroll
    for (int i = 0; i < 4; i++) {
        accA[i] = (floatx4){0.f, 0.f, 0.f, 0.f};
        accB[i] = (floatx4){0.f, 0.f, 0.f, 0.f};
    }
    floatx4 lAcc = (floatx4){0.f, 0.f, 0.f, 0.f};
    floatx4 lBcc = (floatx4){0.f, 0.f, 0.f, 0.f};

    const int srow = w * 16 + (lane >> 3);
    const int sseg = (lane & 7) ^ ((lane >> 3) & 7);
    const u16* kg = QKV + (size_t)(b * T_ + srow) * QS_ + D_ + g * 64 + sseg * 8;
    const u16* vg = Vtr + (size_t)((b * 4 + g) * 64 + srow) * T_ + sseg * 8;
    u16* klds = Kt + w * 1024 + lane * 8;
    u16* vlds = Vs + w * 1024 + lane * 8;

    const int sw0 = (quad ^ (l16 & 7)) * 8;
    const int sw1 = ((4 + quad) ^ (l16 & 7)) * 8;

    async16(kg, klds);
    async16(kg + (size_t)8 * QS_, klds + 512);
    async16(vg, vlds);
    async16(vg + (size_t)8 * T_, vlds + 512);

    for (int tk = 0; tk < nB; tk++) {
        const bool dual = (tk < nA);
        __syncthreads();

        floatx4 SB[4], SA[4];
#pragma unroll
        for (int nt = 0; nt < 4; nt++) {
            const u16* kr = Kt + (nt * 16 + l16) * 64;
            short8 kf0 = *(const short8*)(kr + sw0);
            short8 kf1 = *(const short8*)(kr + sw1);
            SB[nt] = (floatx4){0.f, 0.f, 0.f, 0.f};
            SB[nt] = __builtin_amdgcn_mfma_f32_16x16x32_bf16(kf0, aqB0, SB[nt], 0, 0, 0);
            SB[nt] = __builtin_amdgcn_mfma_f32_16x16x32_bf16(kf1, aqB1, SB[nt], 0, 0, 0);
            if (dual) {
                SA[nt] = (floatx4){0.f, 0.f, 0.f, 0.f};
                SA[nt] = __builtin_amdgcn_mfma_f32_16x16x32_bf16(kf0, aqA0, SA[nt], 0, 0, 0);
                SA[nt] = __builtin_amdgcn_mfma_f32_16x16x32_bf16(kf1, aqA1, SA[nt], 0, 0, 0);
            }
        }
        short8 vf[4][2];
#pragma unroll
        for (int dd = 0; dd < 4; dd++) {
            const u16* vr = Vs + (dd * 16 + l16) * 64;
            vf[dd][0] = *(const short8*)(vr + sw0);
            vf[dd][1] = *(const short8*)(vr + sw1);
        }
        __syncthreads();
        if (tk + 1 < nB) {
            kg += (size_t)64 * QS_;
            vg += 64;
            async16(kg, klds);
            async16(kg + (size_t)8 * QS_, klds + 512);
            async16(vg, vlds);
            async16(vg + (size_t)8 * T_, vlds + 512);
        }

        const bool maskB = (tk == nB - 1);
        const int qB = mB + l16;
#pragma unroll
        for (int nt = 0; nt < 4; nt++) {
            float p[4];
#pragma unroll
            for (int r = 0; r < 4; r++) {
                float e = __builtin_amdgcn_exp2f(SB[nt][r]);
                if (maskB) {
                    int key = tk * 64 + nt * 16 + quad * 4 + r;
                    e = (key <= qB) ? e : 0.f;
                }
                p[r] = e;
            }
            uint2 pw; pw.x = pack_hi(p[0], p[1]); pw.y = pack_hi(p[2], p[3]);
            *(uint2*)&P[w][1][l16][nt * 16 + quad * 4] = pw;
        }
        short8 pfB0 = *(const short8*)&P[w][1][l16][quad * 8];
        short8 pfB1 = *(const short8*)&P[w][1][l16][quad * 8 + 32];
#pragma unroll
        for (int dd = 0; dd < 4; dd++) {
            accB[dd] = __builtin_amdgcn_mfma_f32_16x16x32_bf16(pfB0, vf[dd][0], accB[dd], 0, 0, 0);
            accB[dd] = __builtin_amdgcn_mfma_f32_16x16x32_bf16(pfB1, vf[dd][1], accB[dd], 0, 0, 0);
        }
        lBcc = __builtin_amdgcn_mfma_f32_16x16x32_bf16(pfB0, ones, lBcc, 0, 0, 0);
        lBcc = __builtin_amdgcn_mfma_f32_16x16x32_bf16(pfB1, ones, lBcc, 0, 0, 0);

        if (dual) {
            const bool maskA = (tk == nA - 1);
            const int qA = mA + l16;
#pragma unroll
            for (int nt = 0; nt < 4; nt++) {
                float p[4];
#pragma unroll
                for (int r = 0; r < 4; r++) {
                    float e = __builtin_amdgcn_exp2f(SA[nt][r]);
                    if (maskA) {
                        int key = tk * 64 + nt * 16 + quad * 4 + r;
                        e = (key <= qA) ? e : 0.f;
                    }
                    p[r] = e;
                }
                uint2 pw; pw.x = pack_hi(p[0], p[1]); pw.y = pack_hi(p[2], p[3]);
                *(uint2*)&P[w][0][l16][nt * 16 + quad * 4] = pw;
            }
            short8 pfA0 = *(const short8*)&P[w][0][l16][quad * 8];
            short8 pfA1 = *(const short8*)&P[w][0][l16][quad * 8 + 32];
#pragma unroll
            for (int dd = 0; dd < 4; dd++) {
                accA[dd] = __builtin_amdgcn_mfma_f32_16x16x32_bf16(pfA0, vf[dd][0], accA[dd], 0, 0, 0);
                accA[dd] = __builtin_amdgcn_mfma_f32_16x16x32_bf16(pfA1, vf[dd][1], accA[dd], 0, 0, 0);
            }
            lAcc = __builtin_amdgcn_mfma_f32_16x16x32_bf16(pfA0, ones, lAcc, 0, 0, 0);
            lAcc = __builtin_amdgcn_mfma_f32_16x16x32_bf16(pfA1, ones, lAcc, 0, 0, 0);
        }
    }

#pragma unroll
    for (int r = 0; r < 4; r++) {
        float invA = 1.0f / lAcc[r];
        float invB = 1.0f / lBcc[r];
        int rowA = mA + quad * 4 + r;
        int rowB = mB + quad * 4 + r;
        u16* ypA = Y + (size_t)(b * T_ + rowA) * D_ + h * HD_ + l16;
        u16* ypB = Y + (size_t)(b * T_ + rowB) * D_ + h * HD_ + l16;
#pragma unroll
        for (int dd = 0; dd < 4; dd++) {
            ypA[dd * 16] = f2b(accA[dd][r] * invA);
            ypB[dd * 16] = f2b(accB[dd][r] * invB);
        }
    }
}

// ---------------------------------------------------------------------------
extern "C" void kernel_launch(void* const* d_in, const int* in_sizes, int n_in,
                              void* d_out, int out_size, void* d_ws, size_t ws_size,
                              hipStream_t stream) {
    const float* x    = (const float*)d_in[0];
    const float* Wq   = (const float*)d_in[1];
    const float* Wk   = (const float*)d_in[2];
    const float* Wv   = (const float*)d_in[3];
    const float* Wp   = (const float*)d_in[4];
    const float* gain = (const float*)d_in[5];
    float* out = (float*)d_out;

    u16* xb   = (u16*)d_ws;
    u16* Wcat = xb + (size_t)NX;
    u16* Wpb  = Wcat + (size_t)(NWQ + NWK + NWV);
    u16* QKV  = Wpb + (size_t)NWP;
    u16* Vt   = QKV + (size_t)M_ * QS_;
    u16* Y    = Vt + (size_t)M_ * KV_;
    float2* tab = (float2*)(Y + (size_t)M_ * D_);

    prep<<<CAST_BLOCKS + TAB_BLOCKS, 256, 0, stream>>>(x, Wq, Wk, Wv, Wp, xb, tab);

    gemm_qkv<<<dim3(QS_ / 64, M_ / 128), 256, 0, stream>>>(xb, Wcat, QKV, Vt,
                                                           gain, tab);

    flash<<<dim3(16, H_, B_), 256, 0, stream>>>(QKV, Vt, Y);

    gemm_proj<<<dim3(D_ / 64, M_ / 128), 256, 0, stream>>>(Y, Wpb, out);
}